// Round 8
// baseline (647.139 us; speedup 1.0000x reference)
//
#include <hip/hip_runtime.h>
#include <stdint.h>

#define N_NODES 50000
#define N_EDGES 600000
#define DIM 128
#define NGRAPH 128

typedef __bf16 bf16x8 __attribute__((ext_vector_type(8)));
typedef float f32x4 __attribute__((ext_vector_type(4)));
typedef unsigned short u16;
typedef unsigned int u32;
typedef long long i64;

__device__ __forceinline__ float bf2f(u16 a) {
  union { u32 u; float f; } x; x.u = ((u32)a) << 16; return x.f;
}
__device__ __forceinline__ u16 f2bf(float f) {
  union { float f; u32 u; } x; x.f = f;
  u32 u = x.u;
  u32 r = (u + 0x7FFFu + ((u >> 16) & 1u)) >> 16;
  return (u16)r;
}
__device__ __forceinline__ void unpack8(uint4 v, float* f) {
  f[0] = bf2f((u16)(v.x & 0xFFFF)); f[1] = bf2f((u16)(v.x >> 16));
  f[2] = bf2f((u16)(v.y & 0xFFFF)); f[3] = bf2f((u16)(v.y >> 16));
  f[4] = bf2f((u16)(v.z & 0xFFFF)); f[5] = bf2f((u16)(v.z >> 16));
  f[6] = bf2f((u16)(v.w & 0xFFFF)); f[7] = bf2f((u16)(v.w >> 16));
}

// DPP row-level add: p + dpp(p). CTRL must be a compile-time constant:
// 0xB1=quad_perm [1,0,3,2] (xor1), 0x4E=quad_perm [2,3,0,1] (xor2),
// 0x124=row_ror:4, 0x128=row_ror:8. All within a 16-lane row (our group).
template <int CTRL>
__device__ __forceinline__ float dpp_add(float p) {
  int t = __builtin_amdgcn_update_dpp(0, __float_as_int(p), CTRL, 0xf, 0xf, true);
  return p + __int_as_float(t);
}

// ---------------- sentinel (fp32 out) ----------------
__global__ void sentinel_fill(float* __restrict__ out, int n, float code) {
  int i = blockIdx.x * 256 + threadIdx.x;
  if (i < n) out[i] = code;
}

// ---------------- dtype detection (parallel) + deg zeroing ----------------
__global__ void detect_dtypes(const u16* __restrict__ xu, const int* __restrict__ ei,
                              const int* __restrict__ bat, int* __restrict__ flags,
                              int* __restrict__ deg) {
  int gid = blockIdx.x * 256 + threadIdx.x;    // 32768 threads
  int c0 = 0;
  for (int i = gid; i < 200000; i += 32768) c0 += ((xu[i] & 0x7F80) == 0x7F80) ? 1 : 0;
  if (c0) atomicAdd(&flags[0], c0);
  if (gid < 2048 && ei[1 + gid * 586] != 0) atomicAdd(&flags[1], 1);
  if (gid < 2000 && bat[1 + gid * 24] != 0) atomicAdd(&flags[2], 1);
  for (int i = gid; i < N_NODES; i += 32768) deg[i] = 0;   // zero deg for count_deg
}

__device__ __forceinline__ void load_edge(const int* __restrict__ ei, bool is64, int e,
                                          int& s, int& d) {
  if (is64) {
    s = (int)((const i64*)ei)[e];
    d = (int)((const i64*)ei)[(size_t)N_EDGES + e];
  } else {
    s = ei[e];
    d = ei[N_EDGES + e];
  }
  s = min(max(s, 0), N_NODES - 1);
  d = min(max(d, 0), N_NODES - 1);
}

// ---------------- fused prep: weights (blocks 0-11) + bias (block 12)
//                  + x->bf16 convert (blocks 13+) ----------------
// WT[(l*4+m)][j*128+k] = bf16(W[k][j]); biasc[(l*4+m)*128+d]; Hb = bf16(x).
__global__ void prep_all(const void* __restrict__ Wq, const void* __restrict__ Wk,
                         const void* __restrict__ Wv, const void* __restrict__ Ws,
                         const void* __restrict__ bq, const void* __restrict__ bk,
                         const void* __restrict__ bv, const void* __restrict__ bs,
                         u16* __restrict__ WT, float* __restrict__ biasc,
                         const void* __restrict__ x, u16* __restrict__ Hb,
                         const int* __restrict__ flags) {
  int b = blockIdx.x;
  bool f32 = flags[0] > 0;
  if (b < 12) {
    int l = b >> 2, m = b & 3;
    const void* W = (m == 0 ? Wq : m == 1 ? Wk : m == 2 ? Wv : Ws);
    size_t base = (size_t)l * DIM * DIM;
    u16* out = WT + (size_t)b * DIM * DIM;
    for (int idx = threadIdx.x; idx < DIM * DIM; idx += 256) {
      int j = idx >> 7, k = idx & 127;
      float v;
      if (f32) v = ((const float*)W)[base + (size_t)k * DIM + j];
      else     v = bf2f(((const u16*)W)[base + (size_t)k * DIM + j]);
      out[idx] = f2bf(v);
    }
  } else if (b == 12) {
    for (int idx = threadIdx.x; idx < 12 * DIM; idx += 256) {
      int bb = idx >> 7, d = idx & 127;
      int l = bb >> 2, m = bb & 3;
      const void* p = (m == 0 ? bq : m == 1 ? bk : m == 2 ? bv : bs);
      float v;
      if (f32) v = ((const float*)p)[l * DIM + d];
      else     v = bf2f(((const u16*)p)[l * DIM + d]);
      biasc[idx] = v;
    }
  } else {
    int i = (b - 13) * 256 + threadIdx.x;     // 8-elem chunk id
    const int total = N_NODES * DIM / 8;      // 800000
    if (i >= total) return;
    union { u16 h[8]; uint4 q; } pk;
    if (f32) {
      const float4* xf = (const float4*)x;
      float4 a = xf[(size_t)i * 2], c = xf[(size_t)i * 2 + 1];
      pk.h[0] = f2bf(a.x); pk.h[1] = f2bf(a.y); pk.h[2] = f2bf(a.z); pk.h[3] = f2bf(a.w);
      pk.h[4] = f2bf(c.x); pk.h[5] = f2bf(c.y); pk.h[6] = f2bf(c.z); pk.h[7] = f2bf(c.w);
    } else {
      pk.q = ((const uint4*)x)[i];
    }
    ((uint4*)Hb)[i] = pk.q;
  }
}

// ---------------- fused q/k/v/skip GEMM: bf16 H, one matrix per block ----------
// K and V are written interleaved into KV: row n = [K(n) | V(n)] (512 B) so the
// attention gather touches one contiguous region per edge.
__global__ __launch_bounds__(256) void gemm_qkvs(
    const u16* __restrict__ Hb, const u16* __restrict__ WT,
    const float* __restrict__ biasc,
    u16* __restrict__ Q, u16* __restrict__ KV, u16* __restrict__ S) {
  __shared__ u16 As[64][136];    // 17.4 KB
  __shared__ u16 Bs[128][136];   // 34.8 KB
  int tid = threadIdx.x;
  int r0 = blockIdx.x * 64;
  int mat = blockIdx.y;
  const u16* Wt = WT + (size_t)mat * DIM * DIM;

  for (int it = 0; it < 4; ++it) {
    int i16 = it * 256 + tid;
    int row = i16 >> 4, seg = i16 & 15;
    uint4 val = make_uint4(0, 0, 0, 0);
    if (r0 + row < N_NODES) val = ((const uint4*)Hb)[(size_t)(r0 + row) * 16 + seg];
    *((uint4*)&As[row][seg * 8]) = val;
  }
  for (int it = 0; it < 8; ++it) {
    int i16 = it * 256 + tid;
    int j = i16 >> 4, seg = i16 & 15;
    uint4 val = ((const uint4*)Wt)[j * 16 + seg];
    *((uint4*)&Bs[j][seg * 8]) = val;
  }
  __syncthreads();

  int lane = tid & 63;
  int w = tid >> 6;
  int wm = w & 1, wn = w >> 1;
  int lrow = lane & 15;
  int kq = (lane >> 4) * 8;
  f32x4 acc[2][4] = {};
#pragma unroll
  for (int kt = 0; kt < 4; ++kt) {
    int k0 = kt * 32 + kq;
    bf16x8 a0 = *((const bf16x8*)&As[wm * 32 + lrow][k0]);
    bf16x8 a1 = *((const bf16x8*)&As[wm * 32 + 16 + lrow][k0]);
#pragma unroll
    for (int ni = 0; ni < 4; ++ni) {
      bf16x8 b = *((const bf16x8*)&Bs[wn * 64 + ni * 16 + lrow][k0]);
      acc[0][ni] = __builtin_amdgcn_mfma_f32_16x16x32_bf16(a0, b, acc[0][ni], 0, 0, 0);
      acc[1][ni] = __builtin_amdgcn_mfma_f32_16x16x32_bf16(a1, b, acc[1][ni], 0, 0, 0);
    }
  }

  const float* bias = biasc + mat * DIM;
  u16* Out; int rstride, coff;
  if (mat == 0)      { Out = Q;  rstride = DIM;     coff = 0;   }
  else if (mat == 1) { Out = KV; rstride = 2 * DIM; coff = 0;   }
  else if (mat == 2) { Out = KV; rstride = 2 * DIM; coff = DIM; }
  else               { Out = S;  rstride = DIM;     coff = 0;   }
#pragma unroll
  for (int mi = 0; mi < 2; ++mi)
#pragma unroll
    for (int ni = 0; ni < 4; ++ni) {
      int colg = wn * 64 + ni * 16 + lrow;
      float bvf = bias[colg];
#pragma unroll
      for (int r = 0; r < 4; ++r) {
        int rowg = r0 + wm * 32 + mi * 16 + (lane >> 4) * 4 + r;
        if (rowg < N_NODES) {
          float o = acc[mi][ni][r] + bvf;
          if (!(o - o == 0.0f)) o = 7000.0f;
          Out[(size_t)rowg * rstride + coff + colg] = f2bf(o);
        }
      }
    }
}

// ---------------- CSR build ----------------
__global__ void count_deg(const int* __restrict__ ei, const int* __restrict__ flags,
                          int* __restrict__ deg) {
  int e = blockIdx.x * 256 + threadIdx.x;
  if (e < N_EDGES) {
    int s, d;
    load_edge(ei, flags[1] == 0, e, s, d);
    atomicAdd(&deg[d], 1);
  }
}

// single-block two-pass scan: row_ptr[i+1] = prefix-sum(deg[0..i]), row_ptr[0]=0
__global__ __launch_bounds__(1024) void scan_all(const int* __restrict__ deg,
                                                 int* __restrict__ row_ptr) {
  __shared__ int wsum[16];
  __shared__ int woff[16];
  int tid = threadIdx.x;
  const int CH = 49;                 // 1024*49 = 50176 >= 50000
  int base = tid * CH;
  int tot = 0;
  for (int j = 0; j < CH; ++j) {
    int idx = base + j;
    if (idx < N_NODES) tot += deg[idx];
  }
  int lane = tid & 63;
  int incl = tot;
  for (int off = 1; off < 64; off <<= 1) {
    int t = __shfl_up(incl, off, 64);
    if (lane >= off) incl += t;
  }
  int wv = tid >> 6;                 // 0..15
  if (lane == 63) wsum[wv] = incl;
  __syncthreads();
  if (tid == 0) {
    int r = 0;
    for (int i = 0; i < 16; ++i) { int t = wsum[i]; woff[i] = r; r += t; }
  }
  __syncthreads();
  int run = (incl - tot) + woff[wv]; // exclusive prefix for this thread
  for (int j = 0; j < CH; ++j) {
    int idx = base + j;
    if (idx < N_NODES) { run += deg[idx]; row_ptr[idx + 1] = run; }
  }
  if (tid == 0) row_ptr[0] = 0;
}

__global__ void fill_csr(const int* __restrict__ ei, const int* __restrict__ flags,
                         const int* __restrict__ row_ptr, int* __restrict__ deg,
                         int* __restrict__ csr_src) {
  int e = blockIdx.x * 256 + threadIdx.x;
  if (e < N_EDGES) {
    int s, d;
    load_edge(ei, flags[1] == 0, e, s, d);
    int c = atomicSub(&deg[d], 1);
    int pos = row_ptr[d] + c - 1;
    if (pos >= 0 && pos < N_EDGES) csr_src[pos] = s;
  }
}

// ---------------- attention: 1 wave/node, 4x16, depth-3 register pipeline ----------
// (R3-verified structure: 57.5 us. group g handles edges start+g, start+g+4, ...;
// lane sl covers dims sl*8..+7. Two K/V pairs buffered ahead; csr index prefetched
// one further iteration ahead. KV row n = [K(n)|V(n)] 512 B contiguous. Score
// reduction across the 16-lane group via DPP adds (VALU). Deferred-max THR=8.)
__global__ __launch_bounds__(256, 8) void attn_agg(
    const u16* __restrict__ Q, const u16* __restrict__ KV,
    const u16* __restrict__ S,
    const int* __restrict__ row_ptr, const int* __restrict__ csr_src,
    void* __restrict__ Hout, int apply_relu, int out_f32) {
  int wid = threadIdx.x >> 6;
  int lane = threadIdx.x & 63;
  int n = blockIdx.x * 4 + wid;
  if (n >= N_NODES) return;
  int g = lane >> 4;            // 0..3
  int sl = lane & 15;           // 0..15
  int d0 = sl * 8;
  uint4 qv = *((const uint4*)&Q[(size_t)n * DIM + d0]);
  uint4 sv = *((const uint4*)&S[(size_t)n * DIM + d0]);   // issued early: hides under loop
  float q[8]; unpack8(qv, q);
  int start = row_ptr[n], end = row_ptr[n + 1];
  start = min(max(start, 0), N_EDGES);
  end = min(max(end, start), N_EDGES);
  const float scale = 0.0883883476483184f;  // 1/sqrt(128)
  float m = -INFINITY, lsum = 0.f;
  float acc[8] = {};

  auto PROC = [&](uint4 kc, uint4 vc) {
    float kf[8], vf[8];
    unpack8(kc, kf); unpack8(vc, vf);
    float p = q[0] * kf[0] + q[1] * kf[1] + q[2] * kf[2] + q[3] * kf[3]
            + q[4] * kf[4] + q[5] * kf[5] + q[6] * kf[6] + q[7] * kf[7];
    // 16-lane row reduce, all VALU: quad xor1, quad xor2, then cyclic ror4+ror8
    p = dpp_add<0xB1>(p);    // quad_perm [1,0,3,2]
    p = dpp_add<0x4E>(p);    // quad_perm [2,3,0,1]
    p = dpp_add<0x124>(p);   // row_ror:4
    p = dpp_add<0x128>(p);   // row_ror:8
    float s = p * scale;                 // uniform within the 16-lane group
    if (s - m <= 8.0f) {                 // common: no rescale, P bounded by e^8
      float wv = __expf(s - m);
      lsum += wv;
#pragma unroll
      for (int j = 0; j < 8; ++j) acc[j] = fmaf(wv, vf[j], acc[j]);
    } else {                             // new max (always taken on first edge)
      float wold = __expf(m - s);        // exp(-inf)=0 on first edge
      lsum = fmaf(lsum, wold, 1.0f);
#pragma unroll
      for (int j = 0; j < 8; ++j) acc[j] = fmaf(acc[j], wold, vf[j]);
      m = s;
    }
  };

  int e = start + g;
  uint4 ka = make_uint4(0, 0, 0, 0), va = ka, kb = ka, vb = ka;
  int sA = 0;                           // src for edge e+8
  if (e < end) {
    int s0 = min(max(csr_src[e], 0), N_NODES - 1);
    ka = *((const uint4*)&KV[(size_t)s0 * 2 * DIM + d0]);
    va = *((const uint4*)&KV[(size_t)s0 * 2 * DIM + DIM + d0]);
  }
  if (e + 4 < end) {
    int s1 = min(max(csr_src[e + 4], 0), N_NODES - 1);
    kb = *((const uint4*)&KV[(size_t)s1 * 2 * DIM + d0]);
    vb = *((const uint4*)&KV[(size_t)s1 * 2 * DIM + DIM + d0]);
  }
  if (e + 8 < end) sA = csr_src[e + 8];

  while (e < end) {
    int sN = (e + 12 < end) ? csr_src[e + 12] : 0;
    uint4 kn = make_uint4(0, 0, 0, 0), vn = kn;
    if (e + 8 < end) {
      int srcn = min(max(sA, 0), N_NODES - 1);
      kn = *((const uint4*)&KV[(size_t)srcn * 2 * DIM + d0]);
      vn = *((const uint4*)&KV[(size_t)srcn * 2 * DIM + DIM + d0]);
    }
    PROC(ka, va);
    ka = kb; va = vb; kb = kn; vb = vn; sA = sN;
    e += 4;
  }

  // merge the 4 per-group states (same dims live in lanes sl, sl+16, sl+32, sl+48)
#pragma unroll
  for (int off = 16; off <= 32; off <<= 1) {
    float mo = __shfl_xor(m, off, 64);
    float lo = __shfl_xor(lsum, off, 64);
    float ao[8];
#pragma unroll
    for (int j = 0; j < 8; ++j) ao[j] = __shfl_xor(acc[j], off, 64);
    float mn = fmaxf(m, mo);
    float wa = (m  > -INFINITY) ? __expf(m  - mn) : 0.f;
    float wb = (mo > -INFINITY) ? __expf(mo - mn) : 0.f;
    lsum = lsum * wa + lo * wb;
#pragma unroll
    for (int j = 0; j < 8; ++j) acc[j] = acc[j] * wa + ao[j] * wb;
    m = mn;
  }
  float inv = (lsum > 0.f) ? (1.0f / lsum) : 0.f;
  float sf[8]; unpack8(sv, sf);
  float o[8];
#pragma unroll
  for (int j = 0; j < 8; ++j) {
    float v = acc[j] * inv + sf[j];
    if (apply_relu) v = (v >= 0.f) ? v : 0.01f * v;
    if (!(v - v == 0.0f)) v = 9000.0f;
    o[j] = v;
  }
  if (g == 0) {
    if (out_f32) {
      float* H = (float*)Hout;
      *((float4*)&H[(size_t)n * DIM + d0]) = make_float4(o[0], o[1], o[2], o[3]);
      *((float4*)&H[(size_t)n * DIM + d0 + 4]) = make_float4(o[4], o[5], o[6], o[7]);
    } else {
      union { u16 h[8]; uint4 q; } pk;
#pragma unroll
      for (int j = 0; j < 8; ++j) pk.h[j] = f2bf(o[j]);
      *((uint4*)&((u16*)Hout)[(size_t)n * DIM + d0]) = pk.q;
    }
  }
}

// ---------------- mean pool: one block per graph (batch is sorted) ----------------
__device__ __forceinline__ int bat_at(const int* bat, int i, bool is64) {
  return is64 ? (int)((const i64*)bat)[i] : bat[i];
}

__global__ __launch_bounds__(128) void pool_graph(
    const float* __restrict__ node_emb, const int* __restrict__ bat,
    const int* __restrict__ flags, float* __restrict__ graph_emb) {
  int b = blockIdx.x;           // graph id 0..127
  int t = threadIdx.x;          // dim 0..127
  bool is64 = (flags[2] == 0);
  // lower_bound for b and b+1 over sorted batch
  int lo = 0, hi = N_NODES;
  while (lo < hi) { int mid = (lo + hi) >> 1;
                    if (bat_at(bat, mid, is64) < b) lo = mid + 1; else hi = mid; }
  int lo2 = lo, hi2 = N_NODES;
  while (lo2 < hi2) { int mid = (lo2 + hi2) >> 1;
                      if (bat_at(bat, mid, is64) < b + 1) lo2 = mid + 1; else hi2 = mid; }
  float acc = 0.f;
  for (int i = lo; i < lo2; ++i) acc += node_emb[(size_t)i * DIM + t];
  float g = acc / (float)max(lo2 - lo, 1);
  if (!(g - g == 0.0f)) g = 5555.0f;
  graph_emb[b * DIM + t] = g;
}

extern "C" void kernel_launch(void* const* d_in, const int* in_sizes, int n_in,
                              void* d_out, int out_size, void* d_ws, size_t ws_size,
                              hipStream_t stream) {
  static const int EXP_SIZES[11] = {6400000, 1200000, 50000,
                                    49152, 384, 49152, 384, 49152, 384, 49152, 384};
  {
    float code = 0.0f;
    if (n_in != 11) code = 40000.0f;
    else if (out_size != 6416384) code = 42000.0f;
    else {
      for (int i = 0; i < 11; ++i)
        if (in_sizes[i] != EXP_SIZES[i]) { code = 44000.0f + 400.0f * i; break; }
    }
    if (code != 0.0f) {
      sentinel_fill<<<(out_size + 255) / 256, 256, 0, stream>>>((float*)d_out, out_size, code);
      return;
    }
  }

  const u16* x   = (const u16*)d_in[0];
  const int* ei  = (const int*)d_in[1];
  const int* bat = (const int*)d_in[2];

  const size_t NEEDED = 54465936;
  if (ws_size < NEEDED) {
    float code = 1000.0f + (float)(ws_size >> 20);
    sentinel_fill<<<(out_size + 255) / 256, 256, 0, stream>>>((float*)d_out, out_size, code);
    return;
  }

  char* w = (char*)d_ws;
  int*   flags   = (int*)w;   w += 256;
  int*   blksum  = (int*)w;   w += 256;   (void)blksum;
  float* gsum    = (float*)w; w += (size_t)NGRAPH * DIM * 4;  (void)gsum;
  float* gcnt    = (float*)w; w += (size_t)NGRAPH * 4;        (void)gcnt;
  int*   deg     = (int*)w;   w += (size_t)N_NODES * 4;
  int*   row_ptr = (int*)w;   w += (size_t)(N_NODES + 4) * 4;
  int*   csr_src = (int*)w;   w += (size_t)N_EDGES * 4;
  u16*   WT      = (u16*)w;   w += (size_t)12 * DIM * DIM * 2;
  float* biasc   = (float*)w; w += (size_t)12 * DIM * 4;
  const size_t ND2 = (size_t)N_NODES * DIM * 2;
  u16* Qb  = (u16*)w; w += ND2;
  u16* KVb = (u16*)w; w += 2 * ND2;   // interleaved [K|V] per node
  u16* Sb  = (u16*)w; w += ND2;

  hipMemsetAsync(flags, 0, 256, stream);

  u16* Hb = (u16*)d_out;   // bf16 h aliases d_out node region (fp32) — safe
  detect_dtypes<<<128, 256, 0, stream>>>(x, ei, bat, flags, deg);
  prep_all<<<13 + (N_NODES * DIM / 8 + 255) / 256, 256, 0, stream>>>(
      d_in[3], d_in[5], d_in[7], d_in[9],
      d_in[4], d_in[6], d_in[8], d_in[10],
      WT, biasc, x, Hb, flags);

  int eblocks = (N_EDGES + 255) / 256;
  count_deg<<<eblocks, 256, 0, stream>>>(ei, flags, deg);
  scan_all<<<1, 1024, 0, stream>>>(deg, row_ptr);
  fill_csr<<<eblocks, 256, 0, stream>>>(ei, flags, row_ptr, deg, csr_src);

  float* node_out = (float*)d_out;
  for (int l = 0; l < 3; ++l) {
    gemm_qkvs<<<dim3((N_NODES + 63) / 64, 4), 256, 0, stream>>>(
        Hb, WT + (size_t)l * 4 * DIM * DIM, biasc + (size_t)l * 4 * DIM,
        Qb, KVb, Sb);
    if (l < 2)
      attn_agg<<<(N_NODES + 3) / 4, 256, 0, stream>>>(Qb, KVb, Sb, row_ptr, csr_src,
                                                      (void*)Hb, 1, 0);
    else
      attn_agg<<<(N_NODES + 3) / 4, 256, 0, stream>>>(Qb, KVb, Sb, row_ptr, csr_src,
                                                      (void*)node_out, 0, 1);
  }
  pool_graph<<<NGRAPH, 128, 0, stream>>>(node_out, bat, flags,
                                         node_out + (size_t)N_NODES * DIM);
}

// Round 9
// 494.007 us; speedup vs baseline: 1.3100x; 1.3100x over previous
//
#include <hip/hip_runtime.h>
#include <stdint.h>

#define N_NODES 50000
#define N_EDGES 600000
#define DIM 128
#define NGRAPH 128
#define POOL_ROWS 100

typedef __bf16 bf16x8 __attribute__((ext_vector_type(8)));
typedef float f32x4 __attribute__((ext_vector_type(4)));
typedef unsigned short u16;
typedef unsigned int u32;
typedef long long i64;

__device__ __forceinline__ float bf2f(u16 a) {
  union { u32 u; float f; } x; x.u = ((u32)a) << 16; return x.f;
}
__device__ __forceinline__ u16 f2bf(float f) {
  union { float f; u32 u; } x; x.f = f;
  u32 u = x.u;
  u32 r = (u + 0x7FFFu + ((u >> 16) & 1u)) >> 16;
  return (u16)r;
}
__device__ __forceinline__ void unpack8(uint4 v, float* f) {
  f[0] = bf2f((u16)(v.x & 0xFFFF)); f[1] = bf2f((u16)(v.x >> 16));
  f[2] = bf2f((u16)(v.y & 0xFFFF)); f[3] = bf2f((u16)(v.y >> 16));
  f[4] = bf2f((u16)(v.z & 0xFFFF)); f[5] = bf2f((u16)(v.z >> 16));
  f[6] = bf2f((u16)(v.w & 0xFFFF)); f[7] = bf2f((u16)(v.w >> 16));
}

// DPP row-level add: p + dpp(p). CTRL must be a compile-time constant:
// 0xB1=quad_perm [1,0,3,2] (xor1), 0x4E=quad_perm [2,3,0,1] (xor2),
// 0x124=row_ror:4, 0x128=row_ror:8. All within a 16-lane row (our group).
template <int CTRL>
__device__ __forceinline__ float dpp_add(float p) {
  int t = __builtin_amdgcn_update_dpp(0, __float_as_int(p), CTRL, 0xf, 0xf, true);
  return p + __int_as_float(t);
}

// ---------------- sentinel (fp32 out) ----------------
__global__ void sentinel_fill(float* __restrict__ out, int n, float code) {
  int i = blockIdx.x * 256 + threadIdx.x;
  if (i < n) out[i] = code;
}

// ---------------- dtype detection (parallel) + deg zeroing ----------------
__global__ void detect_dtypes(const u16* __restrict__ xu, const int* __restrict__ ei,
                              const int* __restrict__ bat, int* __restrict__ flags,
                              int* __restrict__ deg) {
  int gid = blockIdx.x * 256 + threadIdx.x;    // 32768 threads
  int c0 = 0;
  for (int i = gid; i < 200000; i += 32768) c0 += ((xu[i] & 0x7F80) == 0x7F80) ? 1 : 0;
  if (c0) atomicAdd(&flags[0], c0);
  if (gid < 2048 && ei[1 + gid * 586] != 0) atomicAdd(&flags[1], 1);
  if (gid < 2000 && bat[1 + gid * 24] != 0) atomicAdd(&flags[2], 1);
  for (int i = gid; i < N_NODES; i += 32768) deg[i] = 0;   // zero deg for count_deg
}

__device__ __forceinline__ void load_edge(const int* __restrict__ ei, bool is64, int e,
                                          int& s, int& d) {
  if (is64) {
    s = (int)((const i64*)ei)[e];
    d = (int)((const i64*)ei)[(size_t)N_EDGES + e];
  } else {
    s = ei[e];
    d = ei[N_EDGES + e];
  }
  s = min(max(s, 0), N_NODES - 1);
  d = min(max(d, 0), N_NODES - 1);
}

// ---------------- fused prep: weights (blocks 0-11) + bias (block 12)
//                  + x->bf16 convert (blocks 13+) ----------------
// WT[(l*4+m)][j*128+k] = bf16(W[k][j]); biasc[(l*4+m)*128+d]; Hb = bf16(x).
__global__ void prep_all(const void* __restrict__ Wq, const void* __restrict__ Wk,
                         const void* __restrict__ Wv, const void* __restrict__ Ws,
                         const void* __restrict__ bq, const void* __restrict__ bk,
                         const void* __restrict__ bv, const void* __restrict__ bs,
                         u16* __restrict__ WT, float* __restrict__ biasc,
                         const void* __restrict__ x, u16* __restrict__ Hb,
                         const int* __restrict__ flags) {
  int b = blockIdx.x;
  bool f32 = flags[0] > 0;
  if (b < 12) {
    int l = b >> 2, m = b & 3;
    const void* W = (m == 0 ? Wq : m == 1 ? Wk : m == 2 ? Wv : Ws);
    size_t base = (size_t)l * DIM * DIM;
    u16* out = WT + (size_t)b * DIM * DIM;
    for (int idx = threadIdx.x; idx < DIM * DIM; idx += 256) {
      int j = idx >> 7, k = idx & 127;
      float v;
      if (f32) v = ((const float*)W)[base + (size_t)k * DIM + j];
      else     v = bf2f(((const u16*)W)[base + (size_t)k * DIM + j]);
      out[idx] = f2bf(v);
    }
  } else if (b == 12) {
    for (int idx = threadIdx.x; idx < 12 * DIM; idx += 256) {
      int bb = idx >> 7, d = idx & 127;
      int l = bb >> 2, m = bb & 3;
      const void* p = (m == 0 ? bq : m == 1 ? bk : m == 2 ? bv : bs);
      float v;
      if (f32) v = ((const float*)p)[l * DIM + d];
      else     v = bf2f(((const u16*)p)[l * DIM + d]);
      biasc[idx] = v;
    }
  } else {
    int i = (b - 13) * 256 + threadIdx.x;     // 8-elem chunk id
    const int total = N_NODES * DIM / 8;      // 800000
    if (i >= total) return;
    union { u16 h[8]; uint4 q; } pk;
    if (f32) {
      const float4* xf = (const float4*)x;
      float4 a = xf[(size_t)i * 2], c = xf[(size_t)i * 2 + 1];
      pk.h[0] = f2bf(a.x); pk.h[1] = f2bf(a.y); pk.h[2] = f2bf(a.z); pk.h[3] = f2bf(a.w);
      pk.h[4] = f2bf(c.x); pk.h[5] = f2bf(c.y); pk.h[6] = f2bf(c.z); pk.h[7] = f2bf(c.w);
    } else {
      pk.q = ((const uint4*)x)[i];
    }
    ((uint4*)Hb)[i] = pk.q;
  }
}

// ---------------- fused q/k/v/skip GEMM: bf16 H, one matrix per block ----------
// K and V are written interleaved into KV: row n = [K(n) | V(n)] (512 B) so the
// attention gather touches one contiguous region per edge.
__global__ __launch_bounds__(256) void gemm_qkvs(
    const u16* __restrict__ Hb, const u16* __restrict__ WT,
    const float* __restrict__ biasc,
    u16* __restrict__ Q, u16* __restrict__ KV, u16* __restrict__ S) {
  __shared__ u16 As[64][136];    // 17.4 KB
  __shared__ u16 Bs[128][136];   // 34.8 KB
  int tid = threadIdx.x;
  int r0 = blockIdx.x * 64;
  int mat = blockIdx.y;
  const u16* Wt = WT + (size_t)mat * DIM * DIM;

  for (int it = 0; it < 4; ++it) {
    int i16 = it * 256 + tid;
    int row = i16 >> 4, seg = i16 & 15;
    uint4 val = make_uint4(0, 0, 0, 0);
    if (r0 + row < N_NODES) val = ((const uint4*)Hb)[(size_t)(r0 + row) * 16 + seg];
    *((uint4*)&As[row][seg * 8]) = val;
  }
  for (int it = 0; it < 8; ++it) {
    int i16 = it * 256 + tid;
    int j = i16 >> 4, seg = i16 & 15;
    uint4 val = ((const uint4*)Wt)[j * 16 + seg];
    *((uint4*)&Bs[j][seg * 8]) = val;
  }
  __syncthreads();

  int lane = tid & 63;
  int w = tid >> 6;
  int wm = w & 1, wn = w >> 1;
  int lrow = lane & 15;
  int kq = (lane >> 4) * 8;
  f32x4 acc[2][4] = {};
#pragma unroll
  for (int kt = 0; kt < 4; ++kt) {
    int k0 = kt * 32 + kq;
    bf16x8 a0 = *((const bf16x8*)&As[wm * 32 + lrow][k0]);
    bf16x8 a1 = *((const bf16x8*)&As[wm * 32 + 16 + lrow][k0]);
#pragma unroll
    for (int ni = 0; ni < 4; ++ni) {
      bf16x8 b = *((const bf16x8*)&Bs[wn * 64 + ni * 16 + lrow][k0]);
      acc[0][ni] = __builtin_amdgcn_mfma_f32_16x16x32_bf16(a0, b, acc[0][ni], 0, 0, 0);
      acc[1][ni] = __builtin_amdgcn_mfma_f32_16x16x32_bf16(a1, b, acc[1][ni], 0, 0, 0);
    }
  }

  const float* bias = biasc + mat * DIM;
  u16* Out; int rstride, coff;
  if (mat == 0)      { Out = Q;  rstride = DIM;     coff = 0;   }
  else if (mat == 1) { Out = KV; rstride = 2 * DIM; coff = 0;   }
  else if (mat == 2) { Out = KV; rstride = 2 * DIM; coff = DIM; }
  else               { Out = S;  rstride = DIM;     coff = 0;   }
#pragma unroll
  for (int mi = 0; mi < 2; ++mi)
#pragma unroll
    for (int ni = 0; ni < 4; ++ni) {
      int colg = wn * 64 + ni * 16 + lrow;
      float bvf = bias[colg];
#pragma unroll
      for (int r = 0; r < 4; ++r) {
        int rowg = r0 + wm * 32 + mi * 16 + (lane >> 4) * 4 + r;
        if (rowg < N_NODES) {
          float o = acc[mi][ni][r] + bvf;
          if (!(o - o == 0.0f)) o = 7000.0f;
          Out[(size_t)rowg * rstride + coff + colg] = f2bf(o);
        }
      }
    }
}

// ---------------- CSR build ----------------
__global__ void count_deg(const int* __restrict__ ei, const int* __restrict__ flags,
                          int* __restrict__ deg) {
  int e = blockIdx.x * 256 + threadIdx.x;
  if (e < N_EDGES) {
    int s, d;
    load_edge(ei, flags[1] == 0, e, s, d);
    atomicAdd(&deg[d], 1);
  }
}

__global__ void scan_blk(const int* __restrict__ deg, int* __restrict__ row_ptr,
                         int* __restrict__ blksum) {
  __shared__ int buf[1024];
  int tid = threadIdx.x;
  int idx = blockIdx.x * 1024 + tid;
  int v = (idx < N_NODES) ? deg[idx] : 0;
  buf[tid] = v;
  __syncthreads();
  for (int off = 1; off < 1024; off <<= 1) {
    int t = (tid >= off) ? buf[tid - off] : 0;
    __syncthreads();
    buf[tid] += t;
    __syncthreads();
  }
  if (idx < N_NODES) row_ptr[idx + 1] = buf[tid];
  if (tid == 1023) blksum[blockIdx.x] = buf[1023];
}

__global__ void scan_sums(int* __restrict__ blksum, int nblk) {
  if (threadIdx.x == 0) {
    int run = 0;
    for (int b = 0; b < nblk; ++b) { int t = blksum[b]; blksum[b] = run; run += t; }
  }
}

__global__ void scan_add(int* __restrict__ row_ptr, const int* __restrict__ blksum) {
  int idx = blockIdx.x * 1024 + threadIdx.x;
  if (idx < N_NODES) row_ptr[idx + 1] += blksum[blockIdx.x];
  if (idx == 0) row_ptr[0] = 0;
}

__global__ void fill_csr(const int* __restrict__ ei, const int* __restrict__ flags,
                         const int* __restrict__ row_ptr, int* __restrict__ deg,
                         int* __restrict__ csr_src) {
  int e = blockIdx.x * 256 + threadIdx.x;
  if (e < N_EDGES) {
    int s, d;
    load_edge(ei, flags[1] == 0, e, s, d);
    int c = atomicSub(&deg[d], 1);
    int pos = row_ptr[d] + c - 1;
    if (pos >= 0 && pos < N_EDGES) csr_src[pos] = s;
  }
}

// ---------------- attention: 1 wave/node, 4x16, depth-3 register pipeline ----------
// (R3-verified structure: 57.5 us best. group g handles edges start+g, start+g+4...;
// lane sl covers dims sl*8..+7. Two K/V pairs buffered ahead; csr index prefetched
// one further iteration ahead. KV row n = [K(n)|V(n)] 512 B contiguous. Score
// reduction across the 16-lane group via DPP adds (VALU). Deferred-max THR=8.)
__global__ __launch_bounds__(256, 8) void attn_agg(
    const u16* __restrict__ Q, const u16* __restrict__ KV,
    const u16* __restrict__ S,
    const int* __restrict__ row_ptr, const int* __restrict__ csr_src,
    void* __restrict__ Hout, int apply_relu, int out_f32) {
  int wid = threadIdx.x >> 6;
  int lane = threadIdx.x & 63;
  int n = blockIdx.x * 4 + wid;
  if (n >= N_NODES) return;
  int g = lane >> 4;            // 0..3
  int sl = lane & 15;           // 0..15
  int d0 = sl * 8;
  uint4 qv = *((const uint4*)&Q[(size_t)n * DIM + d0]);
  uint4 sv = *((const uint4*)&S[(size_t)n * DIM + d0]);   // issued early: hides under loop
  float q[8]; unpack8(qv, q);
  int start = row_ptr[n], end = row_ptr[n + 1];
  start = min(max(start, 0), N_EDGES);
  end = min(max(end, start), N_EDGES);
  const float scale = 0.0883883476483184f;  // 1/sqrt(128)
  float m = -INFINITY, lsum = 0.f;
  float acc[8] = {};

  auto PROC = [&](uint4 kc, uint4 vc) {
    float kf[8], vf[8];
    unpack8(kc, kf); unpack8(vc, vf);
    float p = q[0] * kf[0] + q[1] * kf[1] + q[2] * kf[2] + q[3] * kf[3]
            + q[4] * kf[4] + q[5] * kf[5] + q[6] * kf[6] + q[7] * kf[7];
    // 16-lane row reduce, all VALU: quad xor1, quad xor2, then cyclic ror4+ror8
    p = dpp_add<0xB1>(p);    // quad_perm [1,0,3,2]
    p = dpp_add<0x4E>(p);    // quad_perm [2,3,0,1]
    p = dpp_add<0x124>(p);   // row_ror:4
    p = dpp_add<0x128>(p);   // row_ror:8
    float s = p * scale;                 // uniform within the 16-lane group
    if (s - m <= 8.0f) {                 // common: no rescale, P bounded by e^8
      float wv = __expf(s - m);
      lsum += wv;
#pragma unroll
      for (int j = 0; j < 8; ++j) acc[j] = fmaf(wv, vf[j], acc[j]);
    } else {                             // new max (always taken on first edge)
      float wold = __expf(m - s);        // exp(-inf)=0 on first edge
      lsum = fmaf(lsum, wold, 1.0f);
#pragma unroll
      for (int j = 0; j < 8; ++j) acc[j] = fmaf(acc[j], wold, vf[j]);
      m = s;
    }
  };

  int e = start + g;
  uint4 ka = make_uint4(0, 0, 0, 0), va = ka, kb = ka, vb = ka;
  int sA = 0;                           // src for edge e+8
  if (e < end) {
    int s0 = min(max(csr_src[e], 0), N_NODES - 1);
    ka = *((const uint4*)&KV[(size_t)s0 * 2 * DIM + d0]);
    va = *((const uint4*)&KV[(size_t)s0 * 2 * DIM + DIM + d0]);
  }
  if (e + 4 < end) {
    int s1 = min(max(csr_src[e + 4], 0), N_NODES - 1);
    kb = *((const uint4*)&KV[(size_t)s1 * 2 * DIM + d0]);
    vb = *((const uint4*)&KV[(size_t)s1 * 2 * DIM + DIM + d0]);
  }
  if (e + 8 < end) sA = csr_src[e + 8];

  while (e < end) {
    int sN = (e + 12 < end) ? csr_src[e + 12] : 0;
    uint4 kn = make_uint4(0, 0, 0, 0), vn = kn;
    if (e + 8 < end) {
      int srcn = min(max(sA, 0), N_NODES - 1);
      kn = *((const uint4*)&KV[(size_t)srcn * 2 * DIM + d0]);
      vn = *((const uint4*)&KV[(size_t)srcn * 2 * DIM + DIM + d0]);
    }
    PROC(ka, va);
    ka = kb; va = vb; kb = kn; vb = vn; sA = sN;
    e += 4;
  }

  // merge the 4 per-group states (same dims live in lanes sl, sl+16, sl+32, sl+48)
#pragma unroll
  for (int off = 16; off <= 32; off <<= 1) {
    float mo = __shfl_xor(m, off, 64);
    float lo = __shfl_xor(lsum, off, 64);
    float ao[8];
#pragma unroll
    for (int j = 0; j < 8; ++j) ao[j] = __shfl_xor(acc[j], off, 64);
    float mn = fmaxf(m, mo);
    float wa = (m  > -INFINITY) ? __expf(m  - mn) : 0.f;
    float wb = (mo > -INFINITY) ? __expf(mo - mn) : 0.f;
    lsum = lsum * wa + lo * wb;
#pragma unroll
    for (int j = 0; j < 8; ++j) acc[j] = acc[j] * wa + ao[j] * wb;
    m = mn;
  }
  float inv = (lsum > 0.f) ? (1.0f / lsum) : 0.f;
  float sf[8]; unpack8(sv, sf);
  float o[8];
#pragma unroll
  for (int j = 0; j < 8; ++j) {
    float v = acc[j] * inv + sf[j];
    if (apply_relu) v = (v >= 0.f) ? v : 0.01f * v;
    if (!(v - v == 0.0f)) v = 9000.0f;
    o[j] = v;
  }
  if (g == 0) {
    if (out_f32) {
      float* H = (float*)Hout;
      *((float4*)&H[(size_t)n * DIM + d0]) = make_float4(o[0], o[1], o[2], o[3]);
      *((float4*)&H[(size_t)n * DIM + d0 + 4]) = make_float4(o[4], o[5], o[6], o[7]);
    } else {
      union { u16 h[8]; uint4 q; } pk;
#pragma unroll
      for (int j = 0; j < 8; ++j) pk.h[j] = f2bf(o[j]);
      *((uint4*)&((u16*)Hout)[(size_t)n * DIM + d0]) = pk.q;
    }
  }
}

// ---------------- parallel mean pool ----------------
__device__ __forceinline__ int bat_at(const int* bat, int i, bool is64) {
  return is64 ? (int)((const i64*)bat)[i] : bat[i];
}

__global__ __launch_bounds__(128) void pool_partial(
    const float* __restrict__ node_emb, const int* __restrict__ bat,
    const int* __restrict__ flags, float* __restrict__ gsum, float* __restrict__ gcnt) {
  int t = threadIdx.x;
  int r0 = blockIdx.x * POOL_ROWS;
  int rend = min(r0 + POOL_ROWS, N_NODES);
  if (r0 >= rend) return;
  bool is64 = (flags[2] == 0);
  int cur = min(max(bat_at(bat, r0, is64), 0), NGRAPH - 1);
  float acc = 0.f;
  int cnt = 0;
  for (int i = r0; i < rend; ++i) {
    int b = min(max(bat_at(bat, i, is64), 0), NGRAPH - 1);
    if (b != cur) {
      atomicAdd(&gsum[cur * DIM + t], acc);
      if (t == 0) atomicAdd(&gcnt[cur], (float)cnt);
      acc = 0.f; cnt = 0; cur = b;
    }
    acc += node_emb[(size_t)i * DIM + t];
    ++cnt;
  }
  atomicAdd(&gsum[cur * DIM + t], acc);
  if (t == 0) atomicAdd(&gcnt[cur], (float)cnt);
}

__global__ void pool_final(const float* __restrict__ gsum, const float* __restrict__ gcnt,
                           float* __restrict__ graph_emb) {
  int i = blockIdx.x * 256 + threadIdx.x;
  if (i < NGRAPH * DIM) {
    int b = i >> 7;
    float g = gsum[i] / fmaxf(gcnt[b], 1.0f);
    if (!(g - g == 0.0f)) g = 5555.0f;
    graph_emb[i] = g;
  }
}

extern "C" void kernel_launch(void* const* d_in, const int* in_sizes, int n_in,
                              void* d_out, int out_size, void* d_ws, size_t ws_size,
                              hipStream_t stream) {
  static const int EXP_SIZES[11] = {6400000, 1200000, 50000,
                                    49152, 384, 49152, 384, 49152, 384, 49152, 384};
  {
    float code = 0.0f;
    if (n_in != 11) code = 40000.0f;
    else if (out_size != 6416384) code = 42000.0f;
    else {
      for (int i = 0; i < 11; ++i)
        if (in_sizes[i] != EXP_SIZES[i]) { code = 44000.0f + 400.0f * i; break; }
    }
    if (code != 0.0f) {
      sentinel_fill<<<(out_size + 255) / 256, 256, 0, stream>>>((float*)d_out, out_size, code);
      return;
    }
  }

  const u16* x   = (const u16*)d_in[0];
  const int* ei  = (const int*)d_in[1];
  const int* bat = (const int*)d_in[2];

  const size_t NEEDED = 54465936;
  if (ws_size < NEEDED) {
    float code = 1000.0f + (float)(ws_size >> 20);
    sentinel_fill<<<(out_size + 255) / 256, 256, 0, stream>>>((float*)d_out, out_size, code);
    return;
  }

  char* w = (char*)d_ws;
  int*   flags   = (int*)w;   w += 256;
  int*   blksum  = (int*)w;   w += 256;
  float* gsum    = (float*)w; w += (size_t)NGRAPH * DIM * 4;   // 65536
  float* gcnt    = (float*)w; w += (size_t)NGRAPH * 4;         // 512
  int*   deg     = (int*)w;   w += (size_t)N_NODES * 4;
  int*   row_ptr = (int*)w;   w += (size_t)(N_NODES + 4) * 4;
  int*   csr_src = (int*)w;   w += (size_t)N_EDGES * 4;
  u16*   WT      = (u16*)w;   w += (size_t)12 * DIM * DIM * 2;
  float* biasc   = (float*)w; w += (size_t)12 * DIM * 4;
  const size_t ND2 = (size_t)N_NODES * DIM * 2;
  u16* Qb  = (u16*)w; w += ND2;
  u16* KVb = (u16*)w; w += 2 * ND2;   // interleaved [K|V] per node
  u16* Sb  = (u16*)w; w += ND2;

  // flags + blksum + gsum + gcnt are contiguous: one small memset (deg zeroed in detect)
  hipMemsetAsync(flags, 0, 256 + 256 + (size_t)NGRAPH * DIM * 4 + (size_t)NGRAPH * 4,
                 stream);

  u16* Hb = (u16*)d_out;   // bf16 h aliases d_out node region (fp32) — safe
  detect_dtypes<<<128, 256, 0, stream>>>(x, ei, bat, flags, deg);
  prep_all<<<13 + (N_NODES * DIM / 8 + 255) / 256, 256, 0, stream>>>(
      d_in[3], d_in[5], d_in[7], d_in[9],
      d_in[4], d_in[6], d_in[8], d_in[10],
      WT, biasc, x, Hb, flags);

  int eblocks = (N_EDGES + 255) / 256;
  int nblk = (N_NODES + 1023) / 1024;   // 49
  count_deg<<<eblocks, 256, 0, stream>>>(ei, flags, deg);
  scan_blk<<<nblk, 1024, 0, stream>>>(deg, row_ptr, blksum);
  scan_sums<<<1, 64, 0, stream>>>(blksum, nblk);
  scan_add<<<nblk, 1024, 0, stream>>>(row_ptr, blksum);
  fill_csr<<<eblocks, 256, 0, stream>>>(ei, flags, row_ptr, deg, csr_src);

  float* node_out = (float*)d_out;
  for (int l = 0; l < 3; ++l) {
    gemm_qkvs<<<dim3((N_NODES + 63) / 64, 4), 256, 0, stream>>>(
        Hb, WT + (size_t)l * 4 * DIM * DIM, biasc + (size_t)l * 4 * DIM,
        Qb, KVb, Sb);
    if (l < 2)
      attn_agg<<<(N_NODES + 3) / 4, 256, 0, stream>>>(Qb, KVb, Sb, row_ptr, csr_src,
                                                      (void*)Hb, 1, 0);
    else
      attn_agg<<<(N_NODES + 3) / 4, 256, 0, stream>>>(Qb, KVb, Sb, row_ptr, csr_src,
                                                      (void*)node_out, 0, 1);
  }
  int pblocks = (N_NODES + POOL_ROWS - 1) / POOL_ROWS;   // 500
  pool_partial<<<pblocks, 128, 0, stream>>>(node_out, bat, flags, gsum, gcnt);
  pool_final<<<(NGRAPH * DIM + 255) / 256, 256, 0, stream>>>(gsum, gcnt,
                                                             node_out + (size_t)N_NODES * DIM);
}

// Round 11
// 453.107 us; speedup vs baseline: 1.4282x; 1.0903x over previous
//
#include <hip/hip_runtime.h>
#include <stdint.h>

#define N_NODES 50000
#define N_EDGES 600000
#define DIM 128
#define NGRAPH 128
#define POOL_ROWS 100

typedef __bf16 bf16x8 __attribute__((ext_vector_type(8)));
typedef float f32x4 __attribute__((ext_vector_type(4)));
typedef unsigned short u16;
typedef unsigned int u32;
typedef long long i64;

__device__ __forceinline__ float bf2f(u16 a) {
  union { u32 u; float f; } x; x.u = ((u32)a) << 16; return x.f;
}
__device__ __forceinline__ u16 f2bf(float f) {
  union { float f; u32 u; } x; x.f = f;
  u32 u = x.u;
  u32 r = (u + 0x7FFFu + ((u >> 16) & 1u)) >> 16;
  return (u16)r;
}
__device__ __forceinline__ void unpack8(uint4 v, float* f) {
  f[0] = bf2f((u16)(v.x & 0xFFFF)); f[1] = bf2f((u16)(v.x >> 16));
  f[2] = bf2f((u16)(v.y & 0xFFFF)); f[3] = bf2f((u16)(v.y >> 16));
  f[4] = bf2f((u16)(v.z & 0xFFFF)); f[5] = bf2f((u16)(v.z >> 16));
  f[6] = bf2f((u16)(v.w & 0xFFFF)); f[7] = bf2f((u16)(v.w >> 16));
}

// DPP row-level add: p + dpp(p). CTRL must be a compile-time constant:
// 0xB1=quad_perm [1,0,3,2] (xor1), 0x4E=quad_perm [2,3,0,1] (xor2),
// 0x124=row_ror:4, 0x128=row_ror:8. All within a 16-lane row (our group).
template <int CTRL>
__device__ __forceinline__ float dpp_add(float p) {
  int t = __builtin_amdgcn_update_dpp(0, __float_as_int(p), CTRL, 0xf, 0xf, true);
  return p + __int_as_float(t);
}

// ---------------- sentinel (fp32 out) ----------------
__global__ void sentinel_fill(float* __restrict__ out, int n, float code) {
  int i = blockIdx.x * 256 + threadIdx.x;
  if (i < n) out[i] = code;
}

// ---------------- dtype detection (parallel) + deg zeroing ----------------
__global__ void detect_dtypes(const u16* __restrict__ xu, const int* __restrict__ ei,
                              const int* __restrict__ bat, int* __restrict__ flags,
                              int* __restrict__ deg) {
  int gid = blockIdx.x * 256 + threadIdx.x;    // 32768 threads
  int c0 = 0;
  for (int i = gid; i < 200000; i += 32768) c0 += ((xu[i] & 0x7F80) == 0x7F80) ? 1 : 0;
  if (c0) atomicAdd(&flags[0], c0);
  if (gid < 2048 && ei[1 + gid * 586] != 0) atomicAdd(&flags[1], 1);
  if (gid < 2000 && bat[1 + gid * 24] != 0) atomicAdd(&flags[2], 1);
  for (int i = gid; i < N_NODES; i += 32768) deg[i] = 0;   // zero deg for count_deg
}

__device__ __forceinline__ void load_edge(const int* __restrict__ ei, bool is64, int e,
                                          int& s, int& d) {
  if (is64) {
    s = (int)((const i64*)ei)[e];
    d = (int)((const i64*)ei)[(size_t)N_EDGES + e];
  } else {
    s = ei[e];
    d = ei[N_EDGES + e];
  }
  s = min(max(s, 0), N_NODES - 1);
  d = min(max(d, 0), N_NODES - 1);
}

// ---------------- fused prep: weights (blocks 0-11) + bias (block 12)
//                  + x->bf16 convert (blocks 13+) ----------------
// WT[(l*4+m)][j*128+k] = bf16(W[k][j]); biasc[(l*4+m)*128+d]; Hb = bf16(x).
__global__ void prep_all(const void* __restrict__ Wq, const void* __restrict__ Wk,
                         const void* __restrict__ Wv, const void* __restrict__ Ws,
                         const void* __restrict__ bq, const void* __restrict__ bk,
                         const void* __restrict__ bv, const void* __restrict__ bs,
                         u16* __restrict__ WT, float* __restrict__ biasc,
                         const void* __restrict__ x, u16* __restrict__ Hb,
                         const int* __restrict__ flags) {
  int b = blockIdx.x;
  bool f32 = flags[0] > 0;
  if (b < 12) {
    int l = b >> 2, m = b & 3;
    const void* W = (m == 0 ? Wq : m == 1 ? Wk : m == 2 ? Wv : Ws);
    size_t base = (size_t)l * DIM * DIM;
    u16* out = WT + (size_t)b * DIM * DIM;
    for (int idx = threadIdx.x; idx < DIM * DIM; idx += 256) {
      int j = idx >> 7, k = idx & 127;
      float v;
      if (f32) v = ((const float*)W)[base + (size_t)k * DIM + j];
      else     v = bf2f(((const u16*)W)[base + (size_t)k * DIM + j]);
      out[idx] = f2bf(v);
    }
  } else if (b == 12) {
    for (int idx = threadIdx.x; idx < 12 * DIM; idx += 256) {
      int bb = idx >> 7, d = idx & 127;
      int l = bb >> 2, m = bb & 3;
      const void* p = (m == 0 ? bq : m == 1 ? bk : m == 2 ? bv : bs);
      float v;
      if (f32) v = ((const float*)p)[l * DIM + d];
      else     v = bf2f(((const u16*)p)[l * DIM + d]);
      biasc[idx] = v;
    }
  } else {
    int i = (b - 13) * 256 + threadIdx.x;     // 8-elem chunk id
    const int total = N_NODES * DIM / 8;      // 800000
    if (i >= total) return;
    union { u16 h[8]; uint4 q; } pk;
    if (f32) {
      const float4* xf = (const float4*)x;
      float4 a = xf[(size_t)i * 2], c = xf[(size_t)i * 2 + 1];
      pk.h[0] = f2bf(a.x); pk.h[1] = f2bf(a.y); pk.h[2] = f2bf(a.z); pk.h[3] = f2bf(a.w);
      pk.h[4] = f2bf(c.x); pk.h[5] = f2bf(c.y); pk.h[6] = f2bf(c.z); pk.h[7] = f2bf(c.w);
    } else {
      pk.q = ((const uint4*)x)[i];
    }
    ((uint4*)Hb)[i] = pk.q;
  }
}

// ---------------- fused q/k/v/skip GEMM: bf16 H, one matrix per block ----------
// K and V are written interleaved into KV: row n = [K(n) | V(n)] (512 B).
// Epilogue stages the 64x128 output tile in LDS (reusing As) and stores with
// uint4 (16B/lane, 256B/row bursts) instead of 32 scalar 2B stores per lane.
__global__ __launch_bounds__(256) void gemm_qkvs(
    const u16* __restrict__ Hb, const u16* __restrict__ WT,
    const float* __restrict__ biasc,
    u16* __restrict__ Q, u16* __restrict__ KV, u16* __restrict__ S) {
  __shared__ u16 As[64][136];    // 17.4 KB (reused as output staging)
  __shared__ u16 Bs[128][136];   // 34.8 KB
  int tid = threadIdx.x;
  int r0 = blockIdx.x * 64;
  int mat = blockIdx.y;
  const u16* Wt = WT + (size_t)mat * DIM * DIM;

  for (int it = 0; it < 4; ++it) {
    int i16 = it * 256 + tid;
    int row = i16 >> 4, seg = i16 & 15;
    uint4 val = make_uint4(0, 0, 0, 0);
    if (r0 + row < N_NODES) val = ((const uint4*)Hb)[(size_t)(r0 + row) * 16 + seg];
    *((uint4*)&As[row][seg * 8]) = val;
  }
  for (int it = 0; it < 8; ++it) {
    int i16 = it * 256 + tid;
    int j = i16 >> 4, seg = i16 & 15;
    uint4 val = ((const uint4*)Wt)[j * 16 + seg];
    *((uint4*)&Bs[j][seg * 8]) = val;
  }
  __syncthreads();

  int lane = tid & 63;
  int w = tid >> 6;
  int wm = w & 1, wn = w >> 1;
  int lrow = lane & 15;
  int kq = (lane >> 4) * 8;
  f32x4 acc[2][4] = {};
#pragma unroll
  for (int kt = 0; kt < 4; ++kt) {
    int k0 = kt * 32 + kq;
    bf16x8 a0 = *((const bf16x8*)&As[wm * 32 + lrow][k0]);
    bf16x8 a1 = *((const bf16x8*)&As[wm * 32 + 16 + lrow][k0]);
#pragma unroll
    for (int ni = 0; ni < 4; ++ni) {
      bf16x8 b = *((const bf16x8*)&Bs[wn * 64 + ni * 16 + lrow][k0]);
      acc[0][ni] = __builtin_amdgcn_mfma_f32_16x16x32_bf16(a0, b, acc[0][ni], 0, 0, 0);
      acc[1][ni] = __builtin_amdgcn_mfma_f32_16x16x32_bf16(a1, b, acc[1][ni], 0, 0, 0);
    }
  }

  const float* bias = biasc + mat * DIM;
  u16* Out; int rstride, coff;
  if (mat == 0)      { Out = Q;  rstride = DIM;     coff = 0;   }
  else if (mat == 1) { Out = KV; rstride = 2 * DIM; coff = 0;   }
  else if (mat == 2) { Out = KV; rstride = 2 * DIM; coff = DIM; }
  else               { Out = S;  rstride = DIM;     coff = 0;   }

  __syncthreads();   // all LDS reads of As/Bs complete before As is overwritten
#pragma unroll
  for (int mi = 0; mi < 2; ++mi)
#pragma unroll
    for (int ni = 0; ni < 4; ++ni) {
      int colg = wn * 64 + ni * 16 + lrow;
      float bvf = bias[colg];
#pragma unroll
      for (int r = 0; r < 4; ++r) {
        int rowl = wm * 32 + mi * 16 + (lane >> 4) * 4 + r;   // 0..63
        float o = acc[mi][ni][r] + bvf;
        if (!(o - o == 0.0f)) o = 7000.0f;
        As[rowl][colg] = f2bf(o);
      }
    }
  __syncthreads();
  // 256 threads x 4 uint4 = 64 rows x 16 segs; per wave: 4 x 256B bursts
#pragma unroll
  for (int st = 0; st < 4; ++st) {
    int li = st * 256 + tid;       // 0..1023
    int row = li >> 4, seg = li & 15;
    int rowg = r0 + row;
    if (rowg < N_NODES) {
      uint4 v = *((const uint4*)&As[row][seg * 8]);
      *((uint4*)&Out[(size_t)rowg * rstride + coff + seg * 8]) = v;
    }
  }
}

// ---------------- CSR build ----------------
__global__ void count_deg(const int* __restrict__ ei, const int* __restrict__ flags,
                          int* __restrict__ deg) {
  int e = blockIdx.x * 256 + threadIdx.x;
  if (e < N_EDGES) {
    int s, d;
    load_edge(ei, flags[1] == 0, e, s, d);
    atomicAdd(&deg[d], 1);
  }
}

__global__ void scan_blk(const int* __restrict__ deg, int* __restrict__ row_ptr,
                         int* __restrict__ blksum) {
  __shared__ int buf[1024];
  int tid = threadIdx.x;
  int idx = blockIdx.x * 1024 + tid;
  int v = (idx < N_NODES) ? deg[idx] : 0;
  buf[tid] = v;
  __syncthreads();
  for (int off = 1; off < 1024; off <<= 1) {
    int t = (tid >= off) ? buf[tid - off] : 0;
    __syncthreads();
    buf[tid] += t;
    __syncthreads();
  }
  if (idx < N_NODES) row_ptr[idx + 1] = buf[tid];
  if (tid == 1023) blksum[blockIdx.x] = buf[1023];
}

__global__ void scan_sums(int* __restrict__ blksum, int nblk) {
  if (threadIdx.x == 0) {
    int run = 0;
    for (int b = 0; b < nblk; ++b) { int t = blksum[b]; blksum[b] = run; run += t; }
  }
}

__global__ void scan_add(int* __restrict__ row_ptr, const int* __restrict__ blksum) {
  int idx = blockIdx.x * 1024 + threadIdx.x;
  if (idx < N_NODES) row_ptr[idx + 1] += blksum[blockIdx.x];
  if (idx == 0) row_ptr[0] = 0;
}

__global__ void fill_csr(const int* __restrict__ ei, const int* __restrict__ flags,
                         const int* __restrict__ row_ptr, int* __restrict__ deg,
                         int* __restrict__ csr_src) {
  int e = blockIdx.x * 256 + threadIdx.x;
  if (e < N_EDGES) {
    int s, d;
    load_edge(ei, flags[1] == 0, e, s, d);
    int c = atomicSub(&deg[d], 1);
    int pos = row_ptr[d] + c - 1;
    if (pos >= 0 && pos < N_EDGES) csr_src[pos] = s;
  }
}

// ---------------- attention: 1 wave/node, 4x16, depth-3 register pipeline ----------
// (R3-verified structure: 56.5-57.5 us. group g handles edges start+g, start+g+4...;
// lane sl covers dims sl*8..+7. Two K/V pairs buffered ahead; csr index prefetched
// one further iteration ahead. KV row n = [K(n)|V(n)] 512 B contiguous. Score
// reduction across the 16-lane group via DPP adds (VALU). Deferred-max THR=8.)
__global__ __launch_bounds__(256, 8) void attn_agg(
    const u16* __restrict__ Q, const u16* __restrict__ KV,
    const u16* __restrict__ S,
    const int* __restrict__ row_ptr, const int* __restrict__ csr_src,
    void* __restrict__ Hout, int apply_relu, int out_f32) {
  int wid = threadIdx.x >> 6;
  int lane = threadIdx.x & 63;
  int n = blockIdx.x * 4 + wid;
  if (n >= N_NODES) return;
  int g = lane >> 4;            // 0..3
  int sl = lane & 15;           // 0..15
  int d0 = sl * 8;
  uint4 qv = *((const uint4*)&Q[(size_t)n * DIM + d0]);
  uint4 sv = *((const uint4*)&S[(size_t)n * DIM + d0]);   // issued early: hides under loop
  float q[8]; unpack8(qv, q);
  int start = row_ptr[n], end = row_ptr[n + 1];
  start = min(max(start, 0), N_EDGES);
  end = min(max(end, start), N_EDGES);
  const float scale = 0.0883883476483184f;  // 1/sqrt(128)
  float m = -INFINITY, lsum = 0.f;
  float acc[8] = {};

  auto PROC = [&](uint4 kc, uint4 vc) {
    float kf[8], vf[8];
    unpack8(kc, kf); unpack8(vc, vf);
    float p = q[0] * kf[0] + q[1] * kf[1] + q[2] * kf[2] + q[3] * kf[3]
            + q[4] * kf[4] + q[5] * kf[5] + q[6] * kf[6] + q[7] * kf[7];
    // 16-lane row reduce, all VALU: quad xor1, quad xor2, then cyclic ror4+ror8
    p = dpp_add<0xB1>(p);    // quad_perm [1,0,3,2]
    p = dpp_add<0x4E>(p);    // quad_perm [2,3,0,1]
    p = dpp_add<0x124>(p);   // row_ror:4
    p = dpp_add<0x128>(p);   // row_ror:8
    float s = p * scale;                 // uniform within the 16-lane group
    if (s - m <= 8.0f) {                 // common: no rescale, P bounded by e^8
      float wv = __expf(s - m);
      lsum += wv;
#pragma unroll
      for (int j = 0; j < 8; ++j) acc[j] = fmaf(wv, vf[j], acc[j]);
    } else {                             // new max (always taken on first edge)
      float wold = __expf(m - s);        // exp(-inf)=0 on first edge
      lsum = fmaf(lsum, wold, 1.0f);
#pragma unroll
      for (int j = 0; j < 8; ++j) acc[j] = fmaf(acc[j], wold, vf[j]);
      m = s;
    }
  };

  int e = start + g;
  uint4 ka = make_uint4(0, 0, 0, 0), va = ka, kb = ka, vb = ka;
  int sA = 0;                           // src for edge e+8
  if (e < end) {
    int s0 = min(max(csr_src[e], 0), N_NODES - 1);
    ka = *((const uint4*)&KV[(size_t)s0 * 2 * DIM + d0]);
    va = *((const uint4*)&KV[(size_t)s0 * 2 * DIM + DIM + d0]);
  }
  if (e + 4 < end) {
    int s1 = min(max(csr_src[e + 4], 0), N_NODES - 1);
    kb = *((const uint4*)&KV[(size_t)s1 * 2 * DIM + d0]);
    vb = *((const uint4*)&KV[(size_t)s1 * 2 * DIM + DIM + d0]);
  }
  if (e + 8 < end) sA = csr_src[e + 8];

  while (e < end) {
    int sN = (e + 12 < end) ? csr_src[e + 12] : 0;
    uint4 kn = make_uint4(0, 0, 0, 0), vn = kn;
    if (e + 8 < end) {
      int srcn = min(max(sA, 0), N_NODES - 1);
      kn = *((const uint4*)&KV[(size_t)srcn * 2 * DIM + d0]);
      vn = *((const uint4*)&KV[(size_t)srcn * 2 * DIM + DIM + d0]);
    }
    PROC(ka, va);
    ka = kb; va = vb; kb = kn; vb = vn; sA = sN;
    e += 4;
  }

  // merge the 4 per-group states (same dims live in lanes sl, sl+16, sl+32, sl+48)
#pragma unroll
  for (int off = 16; off <= 32; off <<= 1) {
    float mo = __shfl_xor(m, off, 64);
    float lo = __shfl_xor(lsum, off, 64);
    float ao[8];
#pragma unroll
    for (int j = 0; j < 8; ++j) ao[j] = __shfl_xor(acc[j], off, 64);
    float mn = fmaxf(m, mo);
    float wa = (m  > -INFINITY) ? __expf(m  - mn) : 0.f;
    float wb = (mo > -INFINITY) ? __expf(mo - mn) : 0.f;
    lsum = lsum * wa + lo * wb;
#pragma unroll
    for (int j = 0; j < 8; ++j) acc[j] = acc[j] * wa + ao[j] * wb;
    m = mn;
  }
  float inv = (lsum > 0.f) ? (1.0f / lsum) : 0.f;
  float sf[8]; unpack8(sv, sf);
  float o[8];
#pragma unroll
  for (int j = 0; j < 8; ++j) {
    float v = acc[j] * inv + sf[j];
    if (apply_relu) v = (v >= 0.f) ? v : 0.01f * v;
    if (!(v - v == 0.0f)) v = 9000.0f;
    o[j] = v;
  }
  if (g == 0) {
    if (out_f32) {
      float* H = (float*)Hout;
      *((float4*)&H[(size_t)n * DIM + d0]) = make_float4(o[0], o[1], o[2], o[3]);
      *((float4*)&H[(size_t)n * DIM + d0 + 4]) = make_float4(o[4], o[5], o[6], o[7]);
    } else {
      union { u16 h[8]; uint4 q; } pk;
#pragma unroll
      for (int j = 0; j < 8; ++j) pk.h[j] = f2bf(o[j]);
      *((uint4*)&((u16*)Hout)[(size_t)n * DIM + d0]) = pk.q;
    }
  }
}

// ---------------- parallel mean pool ----------------
__device__ __forceinline__ int bat_at(const int* bat, int i, bool is64) {
  return is64 ? (int)((const i64*)bat)[i] : bat[i];
}

__global__ __launch_bounds__(128) void pool_partial(
    const float* __restrict__ node_emb, const int* __restrict__ bat,
    const int* __restrict__ flags, float* __restrict__ gsum, float* __restrict__ gcnt) {
  int t = threadIdx.x;
  int r0 = blockIdx.x * POOL_ROWS;
  int rend = min(r0 + POOL_ROWS, N_NODES);
  if (r0 >= rend) return;
  bool is64 = (flags[2] == 0);
  int cur = min(max(bat_at(bat, r0, is64), 0), NGRAPH - 1);
  float acc = 0.f;
  int cnt = 0;
  for (int i = r0; i < rend; ++i) {
    int b = min(max(bat_at(bat, i, is64), 0), NGRAPH - 1);
    if (b != cur) {
      atomicAdd(&gsum[cur * DIM + t], acc);
      if (t == 0) atomicAdd(&gcnt[cur], (float)cnt);
      acc = 0.f; cnt = 0; cur = b;
    }
    acc += node_emb[(size_t)i * DIM + t];
    ++cnt;
  }
  atomicAdd(&gsum[cur * DIM + t], acc);
  if (t == 0) atomicAdd(&gcnt[cur], (float)cnt);
}

__global__ void pool_final(const float* __restrict__ gsum, const float* __restrict__ gcnt,
                           float* __restrict__ graph_emb) {
  int i = blockIdx.x * 256 + threadIdx.x;
  if (i < NGRAPH * DIM) {
    int b = i >> 7;
    float g = gsum[i] / fmaxf(gcnt[b], 1.0f);
    if (!(g - g == 0.0f)) g = 5555.0f;
    graph_emb[i] = g;
  }
}

extern "C" void kernel_launch(void* const* d_in, const int* in_sizes, int n_in,
                              void* d_out, int out_size, void* d_ws, size_t ws_size,
                              hipStream_t stream) {
  static const int EXP_SIZES[11] = {6400000, 1200000, 50000,
                                    49152, 384, 49152, 384, 49152, 384, 49152, 384};
  {
    float code = 0.0f;
    if (n_in != 11) code = 40000.0f;
    else if (out_size != 6416384) code = 42000.0f;
    else {
      for (int i = 0; i < 11; ++i)
        if (in_sizes[i] != EXP_SIZES[i]) { code = 44000.0f + 400.0f * i; break; }
    }
    if (code != 0.0f) {
      sentinel_fill<<<(out_size + 255) / 256, 256, 0, stream>>>((float*)d_out, out_size, code);
      return;
    }
  }

  const u16* x   = (const u16*)d_in[0];
  const int* ei  = (const int*)d_in[1];
  const int* bat = (const int*)d_in[2];

  const size_t NEEDED = 54465936;
  if (ws_size < NEEDED) {
    float code = 1000.0f + (float)(ws_size >> 20);
    sentinel_fill<<<(out_size + 255) / 256, 256, 0, stream>>>((float*)d_out, out_size, code);
    return;
  }

  char* w = (char*)d_ws;
  int*   flags   = (int*)w;   w += 256;
  int*   blksum  = (int*)w;   w += 256;
  float* gsum    = (float*)w; w += (size_t)NGRAPH * DIM * 4;   // 65536
  float* gcnt    = (float*)w; w += (size_t)NGRAPH * 4;         // 512
  int*   deg     = (int*)w;   w += (size_t)N_NODES * 4;
  int*   row_ptr = (int*)w;   w += (size_t)(N_NODES + 4) * 4;
  int*   csr_src = (int*)w;   w += (size_t)N_EDGES * 4;
  u16*   WT      = (u16*)w;   w += (size_t)12 * DIM * DIM * 2;
  float* biasc   = (float*)w; w += (size_t)12 * DIM * 4;
  const size_t ND2 = (size_t)N_NODES * DIM * 2;
  u16* Qb  = (u16*)w; w += ND2;
  u16* KVb = (u16*)w; w += 2 * ND2;   // interleaved [K|V] per node
  u16* Sb  = (u16*)w; w += ND2;

  // flags + blksum + gsum + gcnt are contiguous: one small memset (deg zeroed in detect)
  hipMemsetAsync(flags, 0, 256 + 256 + (size_t)NGRAPH * DIM * 4 + (size_t)NGRAPH * 4,
                 stream);

  u16* Hb = (u16*)d_out;   // bf16 h aliases d_out node region (fp32) — safe
  detect_dtypes<<<128, 256, 0, stream>>>(x, ei, bat, flags, deg);
  prep_all<<<13 + (N_NODES * DIM / 8 + 255) / 256, 256, 0, stream>>>(
      d_in[3], d_in[5], d_in[7], d_in[9],
      d_in[4], d_in[6], d_in[8], d_in[10],
      WT, biasc, x, Hb, flags);

  int eblocks = (N_EDGES + 255) / 256;
  int nblk = (N_NODES + 1023) / 1024;   // 49
  count_deg<<<eblocks, 256, 0, stream>>>(ei, flags, deg);
  scan_blk<<<nblk, 1024, 0, stream>>>(deg, row_ptr, blksum);
  scan_sums<<<1, 64, 0, stream>>>(blksum, nblk);
  scan_add<<<nblk, 1024, 0, stream>>>(row_ptr, blksum);
  fill_csr<<<eblocks, 256, 0, stream>>>(ei, flags, row_ptr, deg, csr_src);

  float* node_out = (float*)d_out;
  for (int l = 0; l < 3; ++l) {
    gemm_qkvs<<<dim3((N_NODES + 63) / 64, 4), 256, 0, stream>>>(
        Hb, WT + (size_t)l * 4 * DIM * DIM, biasc + (size_t)l * 4 * DIM,
        Qb, KVb, Sb);
    if (l < 2)
      attn_agg<<<(N_NODES + 3) / 4, 256, 0, stream>>>(Qb, KVb, Sb, row_ptr, csr_src,
                                                      (void*)Hb, 1, 0);
    else
      attn_agg<<<(N_NODES + 3) / 4, 256, 0, stream>>>(Qb, KVb, Sb, row_ptr, csr_src,
                                                      (void*)node_out, 0, 1);
  }
  int pblocks = (N_NODES + POOL_ROWS - 1) / POOL_ROWS;   // 500
  pool_partial<<<pblocks, 128, 0, stream>>>(node_out, bat, flags, gsum, gcnt);
  pool_final<<<(NGRAPH * DIM + 255) / 256, 256, 0, stream>>>(gsum, gcnt,
                                                             node_out + (size_t)N_NODES * DIM);
}